// Round 1
// baseline (3997.004 us; speedup 1.0000x reference)
//
#include <hip/hip_runtime.h>
#include <hip/hip_bf16.h>

#define SEQ 2048
#define DM  1024
#define DI  2048
#define DST 16
#define DTR 64
#define NVOC 32000

__device__ __forceinline__ float siluf(float x) { return x / (1.f + expf(-x)); }
__device__ __forceinline__ float softplusf(float x) {
    return fmaxf(x, 0.f) + log1pf(expf(-fabsf(x)));
}

// h[l,:] = embed[ids[l],:]
__global__ void embed_gather(const int* __restrict__ ids, const float* __restrict__ embed,
                             float* __restrict__ h) {
    int l = blockIdx.x;
    int row = ids[l];
    const float4* src = (const float4*)(embed + (size_t)row * DM);
    float4* dst = (float4*)(h + (size_t)l * DM);
    dst[threadIdx.x] = src[threadIdx.x];   // 256 threads * 4 = 1024 floats
}

// o[l,:] = x[l,:] * rsqrt(mean(x^2)+eps) * w[:]
__global__ void rmsnorm_kernel(const float* __restrict__ x, const float* __restrict__ w,
                               float* __restrict__ o) {
    int l = blockIdx.x;
    int t = threadIdx.x; // 256
    float4 v = ((const float4*)(x + (size_t)l * DM))[t];
    float ss = v.x*v.x + v.y*v.y + v.z*v.z + v.w*v.w;
    #pragma unroll
    for (int m = 32; m; m >>= 1) ss += __shfl_xor(ss, m);
    __shared__ float red[4];
    if ((t & 63) == 0) red[t >> 6] = ss;
    __syncthreads();
    float tot = red[0] + red[1] + red[2] + red[3];
    float sc = rsqrtf(tot * (1.f / DM) + 1e-6f);
    float4 wv = ((const float4*)w)[t];
    float4 ov;
    ov.x = v.x * sc * wv.x;
    ov.y = v.y * sc * wv.y;
    ov.z = v.z * sc * wv.z;
    ov.w = v.w * sc * wv.w;
    ((float4*)(o + (size_t)l * DM))[t] = ov;
}

// Generic fp32 GEMM: C = A(MxK, lda) @ B(KxN) [+bias[n]] [+add] [ACT]
// BM=BN=64, BK=16, 256 threads (16x16), 4x4 per thread.
template<int ACT>
__global__ __launch_bounds__(256) void gemm_f32(const float* __restrict__ A, int lda,
                                                const float* __restrict__ B,
                                                const float* __restrict__ bias,
                                                const float* __restrict__ add,
                                                float* __restrict__ C,
                                                int M, int N, int K) {
    __shared__ float As[16][68];  // [kk][mm], padded
    __shared__ float Bs[16][64];  // [kk][nn]
    int tx = threadIdx.x, ty = threadIdx.y;
    int t = ty * 16 + tx;
    int m0 = blockIdx.y * 64, n0 = blockIdx.x * 64;
    float acc[4][4] = {};
    for (int k0 = 0; k0 < K; k0 += 16) {
        #pragma unroll
        for (int i = 0; i < 4; i++) {
            int idx = t + i * 256;          // 0..1023
            int mm = idx >> 4, kk = idx & 15;
            As[kk][mm] = A[(size_t)(m0 + mm) * lda + k0 + kk];
            int nn = idx & 63, k2 = idx >> 6;
            Bs[k2][nn] = B[(size_t)(k0 + k2) * N + n0 + nn];
        }
        __syncthreads();
        #pragma unroll
        for (int kk = 0; kk < 16; kk++) {
            float4 a = *(const float4*)&As[kk][ty * 4];
            float4 b = *(const float4*)&Bs[kk][tx * 4];
            acc[0][0] += a.x*b.x; acc[0][1] += a.x*b.y; acc[0][2] += a.x*b.z; acc[0][3] += a.x*b.w;
            acc[1][0] += a.y*b.x; acc[1][1] += a.y*b.y; acc[1][2] += a.y*b.z; acc[1][3] += a.y*b.w;
            acc[2][0] += a.z*b.x; acc[2][1] += a.z*b.y; acc[2][2] += a.z*b.z; acc[2][3] += a.z*b.w;
            acc[3][0] += a.w*b.x; acc[3][1] += a.w*b.y; acc[3][2] += a.w*b.z; acc[3][3] += a.w*b.w;
        }
        __syncthreads();
    }
    #pragma unroll
    for (int i = 0; i < 4; i++) {
        int row = m0 + ty * 4 + i;
        float4 r;
        float* pr = &r.x;
        #pragma unroll
        for (int j = 0; j < 4; j++) {
            int col = n0 + tx * 4 + j;
            float v = acc[i][j];
            if (bias) v += bias[col];
            if (add)  v += add[(size_t)row * N + col];
            if (ACT == 1) v = softplusf(v);
            pr[j] = v;
        }
        *(float4*)&C[(size_t)row * N + n0 + tx * 4] = r;
    }
}

// xc[l,d] = silu(conv_b[l] + sum_k x[l, d+k-1] * conv_w[k, l])   (conv over d!)
__global__ void conv_silu_kernel(const float* __restrict__ xr, const float* __restrict__ cw,
                                 const float* __restrict__ cb, float* __restrict__ xc) {
    int idx = blockIdx.x * 256 + threadIdx.x;
    int l = idx >> 11, d = idx & 2047;
    float acc = cb[l];
    const float* xrow = xr + (size_t)l * 4096;   // x part = cols 0..2047
    #pragma unroll
    for (int k = 0; k < 4; k++) {
        int c = d + k - 1;
        if (c >= 0 && c < DI) acc += xrow[c] * cw[k * SEQ + l];
    }
    xc[idx] = siluf(acc);
}

// xdbl[l, 0:96] = u[l,:] @ x_proj_w ; 4 rows per block
__global__ void xproj_kernel(const float* __restrict__ u, const float* __restrict__ xw,
                             float* __restrict__ xdbl) {
    int l0 = blockIdx.x * 4;
    int t = threadIdx.x; // 128
    __shared__ float us[4][DM];
    for (int i = t; i < 4 * DM; i += 128) us[i >> 10][i & 1023] = u[(size_t)l0 * DM + i];
    __syncthreads();
    if (t < 96) {
        float a0 = 0.f, a1 = 0.f, a2 = 0.f, a3 = 0.f;
        for (int k = 0; k < DM; k++) {
            float w = xw[(size_t)k * 96 + t];
            a0 += us[0][k] * w; a1 += us[1][k] * w;
            a2 += us[2][k] * w; a3 += us[3][k] * w;
        }
        xdbl[(size_t)(l0 + 0) * 96 + t] = a0;
        xdbl[(size_t)(l0 + 1) * 96 + t] = a1;
        xdbl[(size_t)(l0 + 2) * 96 + t] = a2;
        xdbl[(size_t)(l0 + 3) * 96 + t] = a3;
    }
}

// Selective scan. Block = 256 threads = 16 d x 16 n. Grid = DI/16 = 128.
// state[d,n] recurrence over l; y[l,d] = sum_n state*C[l,n] + x[l,d]*D[d]
__global__ void scan_kernel(const float* __restrict__ xc, const float* __restrict__ delta,
                            const float* __restrict__ xdbl, const float* __restrict__ A_log,
                            const float* __restrict__ Dp, float* __restrict__ y) {
    int t = threadIdx.x;
    int n = t & 15;
    int dl = t >> 4;             // 0..15
    int d0 = blockIdx.x * 16;
    int d = d0 + dl;
    __shared__ float Bs[64][16], Cs[64][16], dsh[64][16], xsh[64][16];
    float a_dn = -expf(A_log[(size_t)d * DST + n]);
    float Dv = Dp[d];
    float state = 0.f;
    for (int l0 = 0; l0 < SEQ; l0 += 64) {
        #pragma unroll
        for (int i = 0; i < 4; i++) {
            int idx = t + i * 256;       // 0..1023
            int ll = idx >> 4, q = idx & 15;
            size_t lrow = (size_t)(l0 + ll);
            Bs[ll][q]  = xdbl[lrow * 96 + 64 + q];
            Cs[ll][q]  = xdbl[lrow * 96 + 80 + q];
            dsh[ll][q] = delta[lrow * DI + d0 + q];
            xsh[ll][q] = xc[lrow * DI + d0 + q];
        }
        __syncthreads();
        for (int ll = 0; ll < 64; ll++) {
            float dv = dsh[ll][dl];
            float dA = expf(dv * a_dn);
            float dBu = dv * Bs[ll][n] * xsh[ll][dl];
            state = dA * state + dBu;
            float yv = state * Cs[ll][n];
            yv += __shfl_xor(yv, 1);
            yv += __shfl_xor(yv, 2);
            yv += __shfl_xor(yv, 4);
            yv += __shfl_xor(yv, 8);
            if (n == 0) y[(size_t)(l0 + ll) * DI + d] = yv + xsh[ll][dl] * Dv;
        }
        __syncthreads();
    }
}

// y *= silu(res);  res = xr[l, 2048+d]
__global__ void ymul_silu(float* __restrict__ y, const float* __restrict__ xr) {
    int idx = blockIdx.x * 256 + threadIdx.x;
    int l = idx >> 11, d = idx & 2047;
    float res = xr[(size_t)l * 4096 + 2048 + d];
    y[idx] = y[idx] * siluf(res);
}

extern "C" void kernel_launch(void* const* d_in, const int* in_sizes, int n_in,
                              void* d_out, int out_size, void* d_ws, size_t ws_size,
                              hipStream_t stream) {
    const int*   ids        = (const int*)d_in[0];
    const float* embed      = (const float*)d_in[1];
    const float* norm_scale = (const float*)d_in[2];
    const float* in_w       = (const float*)d_in[3];
    const float* in_b       = (const float*)d_in[4];
    const float* conv_w     = (const float*)d_in[5];
    const float* conv_b     = (const float*)d_in[6];
    const float* x_proj_w   = (const float*)d_in[7];
    const float* dt_w       = (const float*)d_in[8];
    const float* dt_b       = (const float*)d_in[9];
    const float* out_w      = (const float*)d_in[10];
    const float* out_b      = (const float*)d_in[11];
    const float* A_log      = (const float*)d_in[12];
    const float* Dp         = (const float*)d_in[13];
    const float* norm_f     = (const float*)d_in[14];
    const float* lm_w       = (const float*)d_in[15];

    float* out = (float*)d_out;
    float* ws  = (float*)d_ws;

    // persistent across layers (workspace, 16 MB total)
    float* h  = ws;                       // 2048*1024
    float* hn = ws + (size_t)SEQ * DM;    // 2048*1024

    // transient scratch inside d_out (262 MB; fully rewritten by final GEMM)
    float* u     = out;                        // 2048*1024
    float* xr    = u + (size_t)SEQ * DM;       // 2048*4096
    float* xc    = xr + (size_t)SEQ * 4096;    // 2048*2048
    float* xdbl  = xc + (size_t)SEQ * DI;      // 2048*96
    float* delta = xdbl + (size_t)SEQ * 96;    // 2048*2048
    float* y     = delta + (size_t)SEQ * DI;   // 2048*2048

    embed_gather<<<SEQ, 256, 0, stream>>>(ids, embed, h);

    for (int L = 0; L < 2; L++) {
        rmsnorm_kernel<<<SEQ, 256, 0, stream>>>(h, norm_scale + (size_t)L * DM, u);
        gemm_f32<0><<<dim3(4096 / 64, SEQ / 64), dim3(16, 16), 0, stream>>>(
            u, DM, in_w + (size_t)L * DM * 4096, in_b + (size_t)L * 4096, nullptr, xr,
            SEQ, 4096, DM);
        conv_silu_kernel<<<SEQ * DI / 256, 256, 0, stream>>>(
            xr, conv_w + (size_t)L * 4 * SEQ, conv_b + (size_t)L * SEQ, xc);
        xproj_kernel<<<SEQ / 4, 128, 0, stream>>>(u, x_proj_w + (size_t)L * DM * 96, xdbl);
        gemm_f32<1><<<dim3(DI / 64, SEQ / 64), dim3(16, 16), 0, stream>>>(
            xdbl, 96, dt_w + (size_t)L * DTR * DI, dt_b + (size_t)L * DI, nullptr, delta,
            SEQ, DI, DTR);
        scan_kernel<<<DI / 16, 256, 0, stream>>>(
            xc, delta, xdbl, A_log + (size_t)L * DI * DST, Dp + (size_t)L * DI, y);
        ymul_silu<<<SEQ * DI / 256, 256, 0, stream>>>(y, xr);
        gemm_f32<0><<<dim3(DM / 64, SEQ / 64), dim3(16, 16), 0, stream>>>(
            y, DI, out_w + (size_t)L * DI * DM, out_b + (size_t)L * DM, h, h,
            SEQ, DM, DI);
    }

    rmsnorm_kernel<<<SEQ, 256, 0, stream>>>(h, norm_f, hn);
    gemm_f32<0><<<dim3(NVOC / 64, SEQ / 64), dim3(16, 16), 0, stream>>>(
        hn, DM, lm_w, nullptr, nullptr, out, SEQ, NVOC, DM);
}

// Round 2
// 1744.422 us; speedup vs baseline: 2.2913x; 2.2913x over previous
//
#include <hip/hip_runtime.h>
#include <hip/hip_bf16.h>

#define SEQ 2048
#define DM  1024
#define DI  2048
#define DST 16
#define DTR 64
#define NVOC 32000

typedef __bf16 bf16x8 __attribute__((ext_vector_type(8)));
typedef float  f32x4  __attribute__((ext_vector_type(4)));

__device__ __forceinline__ float siluf(float x) { return x / (1.f + expf(-x)); }
__device__ __forceinline__ float softplusf(float x) {
    return fmaxf(x, 0.f) + log1pf(expf(-fabsf(x)));
}
__device__ __forceinline__ unsigned short f2bf(float f) {
    union { __hip_bfloat16 h; unsigned short u; } c;
    c.h = __float2bfloat16(f);
    return c.u;
}

// h[l,:] = embed[ids[l],:]
__global__ void embed_gather(const int* __restrict__ ids, const float* __restrict__ embed,
                             float* __restrict__ h) {
    int l = blockIdx.x;
    int row = ids[l];
    const float4* src = (const float4*)(embed + (size_t)row * DM);
    float4* dst = (float4*)(h + (size_t)l * DM);
    dst[threadIdx.x] = src[threadIdx.x];
}

// o[l,:] = x[l,:]*rsqrt(mean(x^2)+eps)*w[:]; optional bf16 copy in ob
__global__ void rmsnorm_kernel(const float* __restrict__ x, const float* __restrict__ w,
                               float* __restrict__ o, unsigned short* __restrict__ ob) {
    int l = blockIdx.x;
    int t = threadIdx.x; // 256
    float4 v = ((const float4*)(x + (size_t)l * DM))[t];
    float ss = v.x*v.x + v.y*v.y + v.z*v.z + v.w*v.w;
    #pragma unroll
    for (int m = 32; m; m >>= 1) ss += __shfl_xor(ss, m);
    __shared__ float red[4];
    if ((t & 63) == 0) red[t >> 6] = ss;
    __syncthreads();
    float tot = red[0] + red[1] + red[2] + red[3];
    float sc = rsqrtf(tot * (1.f / DM) + 1e-6f);
    float4 wv = ((const float4*)w)[t];
    float4 ov;
    ov.x = v.x * sc * wv.x;
    ov.y = v.y * sc * wv.y;
    ov.z = v.z * sc * wv.z;
    ov.w = v.w * sc * wv.w;
    ((float4*)(o + (size_t)l * DM))[t] = ov;
    if (ob) {
        uint2 pk;
        pk.x = (unsigned)f2bf(ov.x) | ((unsigned)f2bf(ov.y) << 16);
        pk.y = (unsigned)f2bf(ov.z) | ((unsigned)f2bf(ov.w) << 16);
        ((uint2*)(ob + (size_t)l * DM))[t] = pk;
    }
}

// W fp32 [K][N] -> WT bf16 [N][K]
__global__ void transpose_f2bf(const float* __restrict__ W, unsigned short* __restrict__ WT,
                               int K, int N) {
    __shared__ float tile[32][33];
    int k0 = blockIdx.y * 32, n0 = blockIdx.x * 32;
    int tx = threadIdx.x;  // 32
    int ty = threadIdx.y;  // 8
    #pragma unroll
    for (int i = 0; i < 32; i += 8)
        tile[ty + i][tx] = W[(size_t)(k0 + ty + i) * N + n0 + tx];
    __syncthreads();
    #pragma unroll
    for (int i = 0; i < 32; i += 8)
        WT[(size_t)(n0 + ty + i) * K + k0 + tx] = f2bf(tile[tx][ty + i]);
}

// Generic fp32 GEMM (fallback + small dt_proj): C = A(MxK, lda)@B(KxN) [+bias][+add][ACT]
template<int ACT>
__global__ __launch_bounds__(256) void gemm_f32(const float* __restrict__ A, int lda,
                                                const float* __restrict__ B,
                                                const float* __restrict__ bias,
                                                const float* __restrict__ add,
                                                float* __restrict__ C,
                                                int M, int N, int K) {
    __shared__ float As[16][68];
    __shared__ float Bs[16][64];
    int tx = threadIdx.x, ty = threadIdx.y;
    int t = ty * 16 + tx;
    int m0 = blockIdx.y * 64, n0 = blockIdx.x * 64;
    float acc[4][4] = {};
    for (int k0 = 0; k0 < K; k0 += 16) {
        #pragma unroll
        for (int i = 0; i < 4; i++) {
            int idx = t + i * 256;
            int mm = idx >> 4, kk = idx & 15;
            As[kk][mm] = A[(size_t)(m0 + mm) * lda + k0 + kk];
            int nn = idx & 63, k2 = idx >> 6;
            Bs[k2][nn] = B[(size_t)(k0 + k2) * N + n0 + nn];
        }
        __syncthreads();
        #pragma unroll
        for (int kk = 0; kk < 16; kk++) {
            float4 a = *(const float4*)&As[kk][ty * 4];
            float4 b = *(const float4*)&Bs[kk][tx * 4];
            acc[0][0] += a.x*b.x; acc[0][1] += a.x*b.y; acc[0][2] += a.x*b.z; acc[0][3] += a.x*b.w;
            acc[1][0] += a.y*b.x; acc[1][1] += a.y*b.y; acc[1][2] += a.y*b.z; acc[1][3] += a.y*b.w;
            acc[2][0] += a.z*b.x; acc[2][1] += a.z*b.y; acc[2][2] += a.z*b.z; acc[2][3] += a.z*b.w;
            acc[3][0] += a.w*b.x; acc[3][1] += a.w*b.y; acc[3][2] += a.w*b.z; acc[3][3] += a.w*b.w;
        }
        __syncthreads();
    }
    #pragma unroll
    for (int i = 0; i < 4; i++) {
        int row = m0 + ty * 4 + i;
        float4 r;
        float* pr = &r.x;
        #pragma unroll
        for (int j = 0; j < 4; j++) {
            int col = n0 + tx * 4 + j;
            float v = acc[i][j];
            if (bias) v += bias[col];
            if (add)  v += add[(size_t)row * N + col];
            if (ACT == 1) v = softplusf(v);
            pr[j] = v;
        }
        *(float4*)&C[(size_t)row * N + n0 + tx * 4] = r;
    }
}

// bf16 MFMA GEMM (m97 structure): C(MxN,f32) = A(bf16 [M][K]) @ BT(bf16 [N][K])^T
// 128x128 tile, BK=32, 256 threads = 4 waves (2x2), 4x4 fragments of 16x16x32.
template<int BIAS, int ADD>
__global__ __launch_bounds__(256) void gemm_bf16(const unsigned short* __restrict__ A,
                                                 const unsigned short* __restrict__ BT,
                                                 const float* __restrict__ bias,
                                                 const float* __restrict__ add,
                                                 float* __restrict__ C,
                                                 int M, int N, int K) {
    __shared__ unsigned short As[128 * 32];
    __shared__ unsigned short Bs[128 * 32];
    int t = threadIdx.x;
    int w = t >> 6, l = t & 63;
    int wm = w >> 1, wn = w & 1;
    int m0 = blockIdx.x * 128;   // M-tiles on x: consecutive blocks share B panel (L2)
    int n0 = blockIdx.y * 128;
    int lr = l & 15, lk = (l >> 4) * 8;
    int sr = t >> 2, sc = (t & 3) * 8;     // staging: row, k-offset
    f32x4 acc[4][4] = {};
    for (int k0 = 0; k0 < K; k0 += 32) {
        const unsigned short* ga = A  + (size_t)(m0 + sr) * K + k0 + sc;
        const unsigned short* gb = BT + (size_t)(n0 + sr) * K + k0 + sc;
        unsigned short* la = As + w * 512;   // wave-uniform base; HW adds lane*16B
        unsigned short* lb = Bs + w * 512;
        __builtin_amdgcn_global_load_lds((const __attribute__((address_space(1))) void*)ga,
            (__attribute__((address_space(3))) void*)la, 16, 0, 0);
        __builtin_amdgcn_global_load_lds((const __attribute__((address_space(1))) void*)(ga + (size_t)64 * K),
            (__attribute__((address_space(3))) void*)(la + 2048), 16, 0, 0);
        __builtin_amdgcn_global_load_lds((const __attribute__((address_space(1))) void*)gb,
            (__attribute__((address_space(3))) void*)lb, 16, 0, 0);
        __builtin_amdgcn_global_load_lds((const __attribute__((address_space(1))) void*)(gb + (size_t)64 * K),
            (__attribute__((address_space(3))) void*)(lb + 2048), 16, 0, 0);
        __syncthreads();
        bf16x8 af[4], bfr[4];
        #pragma unroll
        for (int i = 0; i < 4; i++) {
            af[i]  = *reinterpret_cast<const bf16x8*>(&As[(wm * 64 + i * 16 + lr) * 32 + lk]);
            bfr[i] = *reinterpret_cast<const bf16x8*>(&Bs[(wn * 64 + i * 16 + lr) * 32 + lk]);
        }
        #pragma unroll
        for (int i = 0; i < 4; i++)
            #pragma unroll
            for (int j = 0; j < 4; j++)
                acc[i][j] = __builtin_amdgcn_mfma_f32_16x16x32_bf16(af[i], bfr[j], acc[i][j], 0, 0, 0);
        __syncthreads();
    }
    int cr = (l >> 4) * 4;
    #pragma unroll
    for (int i = 0; i < 4; i++) {
        #pragma unroll
        for (int j = 0; j < 4; j++) {
            int col = n0 + wn * 64 + j * 16 + lr;
            float bv = BIAS ? bias[col] : 0.f;
            #pragma unroll
            for (int rr = 0; rr < 4; rr++) {
                int row = m0 + wm * 64 + i * 16 + cr + rr;
                float v = acc[i][j][rr] + bv;
                if (ADD) v += add[(size_t)row * N + col];
                C[(size_t)row * N + col] = v;
            }
        }
    }
}

// xc[l,d] = silu(conv_b[l] + sum_k x[l, d+k-1]*conv_w[k,l])   (conv over d!)
__global__ void conv_silu_kernel(const float* __restrict__ xr, const float* __restrict__ cw,
                                 const float* __restrict__ cb, float* __restrict__ xc) {
    int idx = blockIdx.x * 256 + threadIdx.x;
    int l = idx >> 11, d = idx & 2047;
    float acc = cb[l];
    const float* xrow = xr + (size_t)l * 4096;
    #pragma unroll
    for (int k = 0; k < 4; k++) {
        int c = d + k - 1;
        if (c >= 0 && c < DI) acc += xrow[c] * cw[k * SEQ + l];
    }
    xc[idx] = siluf(acc);
}

// xdbl[l, 0:96] = u[l,:] @ x_proj_w ; 4 rows per block
__global__ void xproj_kernel(const float* __restrict__ u, const float* __restrict__ xw,
                             float* __restrict__ xdbl) {
    int l0 = blockIdx.x * 4;
    int t = threadIdx.x; // 128
    __shared__ float us[4][DM];
    for (int i = t; i < 4 * DM; i += 128) us[i >> 10][i & 1023] = u[(size_t)l0 * DM + i];
    __syncthreads();
    if (t < 96) {
        float a0 = 0.f, a1 = 0.f, a2 = 0.f, a3 = 0.f;
        for (int k = 0; k < DM; k++) {
            float wv = xw[(size_t)k * 96 + t];
            a0 += us[0][k] * wv; a1 += us[1][k] * wv;
            a2 += us[2][k] * wv; a3 += us[3][k] * wv;
        }
        xdbl[(size_t)(l0 + 0) * 96 + t] = a0;
        xdbl[(size_t)(l0 + 1) * 96 + t] = a1;
        xdbl[(size_t)(l0 + 2) * 96 + t] = a2;
        xdbl[(size_t)(l0 + 3) * 96 + t] = a3;
    }
}

// Selective scan. Block = 256 threads = 16 d x 16 n. Grid = DI/16 = 128.
__global__ void scan_kernel(const float* __restrict__ xc, const float* __restrict__ delta,
                            const float* __restrict__ xdbl, const float* __restrict__ A_log,
                            const float* __restrict__ Dp, float* __restrict__ y) {
    int t = threadIdx.x;
    int n = t & 15;
    int dl = t >> 4;
    int d0 = blockIdx.x * 16;
    int d = d0 + dl;
    __shared__ float Bs[64][16], Cs[64][16], dsh[64][16], xsh[64][16];
    float a_dn = -expf(A_log[(size_t)d * DST + n]);
    float Dv = Dp[d];
    float state = 0.f;
    for (int l0 = 0; l0 < SEQ; l0 += 64) {
        #pragma unroll
        for (int i = 0; i < 4; i++) {
            int idx = t + i * 256;
            int ll = idx >> 4, q = idx & 15;
            size_t lrow = (size_t)(l0 + ll);
            Bs[ll][q]  = xdbl[lrow * 96 + 64 + q];
            Cs[ll][q]  = xdbl[lrow * 96 + 80 + q];
            dsh[ll][q] = delta[lrow * DI + d0 + q];
            xsh[ll][q] = xc[lrow * DI + d0 + q];
        }
        __syncthreads();
        for (int ll = 0; ll < 64; ll++) {
            float dv = dsh[ll][dl];
            float dA = expf(dv * a_dn);
            float dBu = dv * Bs[ll][n] * xsh[ll][dl];
            state = dA * state + dBu;
            float yv = state * Cs[ll][n];
            yv += __shfl_xor(yv, 1);
            yv += __shfl_xor(yv, 2);
            yv += __shfl_xor(yv, 4);
            yv += __shfl_xor(yv, 8);
            if (n == 0) y[(size_t)(l0 + ll) * DI + d] = yv + xsh[ll][dl] * Dv;
        }
        __syncthreads();
    }
}

// y *= silu(res); optional bf16 copy
__global__ void ymul_silu(float* __restrict__ y, const float* __restrict__ xr,
                          unsigned short* __restrict__ yb) {
    int idx = blockIdx.x * 256 + threadIdx.x;
    int l = idx >> 11, d = idx & 2047;
    float res = xr[(size_t)l * 4096 + 2048 + d];
    float v = y[idx] * siluf(res);
    y[idx] = v;
    if (yb) yb[idx] = f2bf(v);
}

extern "C" void kernel_launch(void* const* d_in, const int* in_sizes, int n_in,
                              void* d_out, int out_size, void* d_ws, size_t ws_size,
                              hipStream_t stream) {
    const int*   ids        = (const int*)d_in[0];
    const float* embed      = (const float*)d_in[1];
    const float* norm_scale = (const float*)d_in[2];
    const float* in_w       = (const float*)d_in[3];
    const float* in_b       = (const float*)d_in[4];
    const float* conv_w     = (const float*)d_in[5];
    const float* conv_b     = (const float*)d_in[6];
    const float* x_proj_w   = (const float*)d_in[7];
    const float* dt_w       = (const float*)d_in[8];
    const float* dt_b       = (const float*)d_in[9];
    const float* out_w      = (const float*)d_in[10];
    const float* out_b      = (const float*)d_in[11];
    const float* A_log      = (const float*)d_in[12];
    const float* Dp         = (const float*)d_in[13];
    const float* norm_f     = (const float*)d_in[14];
    const float* lm_w       = (const float*)d_in[15];

    float* out = (float*)d_out;

    // ---- workspace layout ----
    char* p = (char*)d_ws;
    float* h  = (float*)p;  p += (size_t)SEQ * DM * 4;
    float* hn = (float*)p;  p += (size_t)SEQ * DM * 4;
    size_t base = (size_t)p - (size_t)d_ws;
    const size_t SZ_UB   = (size_t)SEQ * DM * 2;
    const size_t SZ_YB   = (size_t)SEQ * DI * 2;
    const size_t SZ_HNB  = (size_t)SEQ * DM * 2;
    const size_t SZ_INWT = (size_t)2 * 4096 * DM * 2;
    const size_t SZ_OUTWT= (size_t)2 * DM * DI * 2;
    const size_t SZ_LMWT = (size_t)NVOC * DM * 2;
    size_t need_mid  = base + SZ_UB + SZ_YB + SZ_HNB + SZ_INWT + SZ_OUTWT;
    size_t need_full = need_mid + SZ_LMWT;
    bool mid  = ws_size >= need_mid;
    bool full = ws_size >= need_full;

    unsigned short *u_b = nullptr, *y_b = nullptr, *hn_b = nullptr;
    unsigned short *in_wT = nullptr, *out_wT = nullptr, *lm_wT = nullptr;
    if (mid) {
        u_b    = (unsigned short*)p; p += SZ_UB;
        y_b    = (unsigned short*)p; p += SZ_YB;
        hn_b   = (unsigned short*)p; p += SZ_HNB;
        in_wT  = (unsigned short*)p; p += SZ_INWT;
        out_wT = (unsigned short*)p; p += SZ_OUTWT;
        if (full) { lm_wT = (unsigned short*)p; p += SZ_LMWT; }
    }

    // transient scratch inside d_out (fully rewritten by final GEMM)
    float* u     = out;                        // 2048*1024
    float* xr    = u + (size_t)SEQ * DM;       // 2048*4096
    float* xc    = xr + (size_t)SEQ * 4096;    // 2048*2048
    float* xdbl  = xc + (size_t)SEQ * DI;      // 2048*96
    float* delta = xdbl + (size_t)SEQ * 96;    // 2048*2048
    float* y     = delta + (size_t)SEQ * DI;   // 2048*2048

    // ---- weight convert+transpose (per call; deterministic) ----
    if (mid) {
        for (int L = 0; L < 2; L++) {
            transpose_f2bf<<<dim3(4096 / 32, DM / 32), dim3(32, 8), 0, stream>>>(
                in_w + (size_t)L * DM * 4096, in_wT + (size_t)L * 4096 * DM, DM, 4096);
            transpose_f2bf<<<dim3(DM / 32, DI / 32), dim3(32, 8), 0, stream>>>(
                out_w + (size_t)L * DI * DM, out_wT + (size_t)L * DM * DI, DI, DM);
        }
        if (full)
            transpose_f2bf<<<dim3(NVOC / 32, DM / 32), dim3(32, 8), 0, stream>>>(
                lm_w, lm_wT, DM, NVOC);
    }

    embed_gather<<<SEQ, 256, 0, stream>>>(ids, embed, h);

    for (int L = 0; L < 2; L++) {
        rmsnorm_kernel<<<SEQ, 256, 0, stream>>>(h, norm_scale + (size_t)L * DM, u, u_b);
        if (mid) {
            gemm_bf16<1, 0><<<dim3(SEQ / 128, 4096 / 128), 256, 0, stream>>>(
                u_b, in_wT + (size_t)L * 4096 * DM, in_b + (size_t)L * 4096, nullptr, xr,
                SEQ, 4096, DM);
        } else {
            gemm_f32<0><<<dim3(4096 / 64, SEQ / 64), dim3(16, 16), 0, stream>>>(
                u, DM, in_w + (size_t)L * DM * 4096, in_b + (size_t)L * 4096, nullptr, xr,
                SEQ, 4096, DM);
        }
        conv_silu_kernel<<<SEQ * DI / 256, 256, 0, stream>>>(
            xr, conv_w + (size_t)L * 4 * SEQ, conv_b + (size_t)L * SEQ, xc);
        xproj_kernel<<<SEQ / 4, 128, 0, stream>>>(u, x_proj_w + (size_t)L * DM * 96, xdbl);
        gemm_f32<1><<<dim3(DI / 64, SEQ / 64), dim3(16, 16), 0, stream>>>(
            xdbl, 96, dt_w + (size_t)L * DTR * DI, dt_b + (size_t)L * DI, nullptr, delta,
            SEQ, DI, DTR);
        scan_kernel<<<DI / 16, 256, 0, stream>>>(
            xc, delta, xdbl, A_log + (size_t)L * DI * DST, Dp + (size_t)L * DI, y);
        ymul_silu<<<SEQ * DI / 256, 256, 0, stream>>>(y, xr, y_b);
        if (mid) {
            gemm_bf16<1, 1><<<dim3(SEQ / 128, DM / 128), 256, 0, stream>>>(
                y_b, out_wT + (size_t)L * DM * DI, out_b + (size_t)L * DM, h, h,
                SEQ, DM, DI);
        } else {
            gemm_f32<0><<<dim3(DM / 64, SEQ / 64), dim3(16, 16), 0, stream>>>(
                y, DI, out_w + (size_t)L * DI * DM, out_b + (size_t)L * DM, h, h,
                SEQ, DM, DI);
        }
    }

    rmsnorm_kernel<<<SEQ, 256, 0, stream>>>(h, norm_f, hn, hn_b);
    if (full) {
        gemm_bf16<0, 0><<<dim3(SEQ / 128, NVOC / 128), 256, 0, stream>>>(
            hn_b, lm_wT, nullptr, nullptr, out, SEQ, NVOC, DM);
    } else {
        gemm_f32<0><<<dim3(NVOC / 64, SEQ / 64), dim3(16, 16), 0, stream>>>(
            hn, DM, lm_w, nullptr, nullptr, out, SEQ, NVOC, DM);
    }
}

// Round 3
// 917.482 us; speedup vs baseline: 4.3565x; 1.9013x over previous
//
#include <hip/hip_runtime.h>
#include <hip/hip_bf16.h>

#define SEQ 2048
#define DM  1024
#define DI  2048
#define DST 16
#define DTR 64
#define NVOC 32000
#define NC  128   // scan chunks
#define LC  16    // chunk length; NC*LC == SEQ

typedef __bf16 bf16x8 __attribute__((ext_vector_type(8)));
typedef float  f32x4  __attribute__((ext_vector_type(4)));

__device__ __forceinline__ float siluf(float x) { return x / (1.f + expf(-x)); }
__device__ __forceinline__ float softplusf(float x) {
    return fmaxf(x, 0.f) + log1pf(expf(-fabsf(x)));
}
__device__ __forceinline__ unsigned short f2bf(float f) {
    union { __hip_bfloat16 h; unsigned short u; } c;
    c.h = __float2bfloat16(f);
    return c.u;
}

// h[l,:] = embed[ids[l],:]
__global__ void embed_gather(const int* __restrict__ ids, const float* __restrict__ embed,
                             float* __restrict__ h) {
    int l = blockIdx.x;
    int row = ids[l];
    const float4* src = (const float4*)(embed + (size_t)row * DM);
    float4* dst = (float4*)(h + (size_t)l * DM);
    dst[threadIdx.x] = src[threadIdx.x];
}

// o[l,:] = x[l,:]*rsqrt(mean(x^2)+eps)*w[:]; optional bf16 copy in ob
__global__ void rmsnorm_kernel(const float* __restrict__ x, const float* __restrict__ w,
                               float* __restrict__ o, unsigned short* __restrict__ ob) {
    int l = blockIdx.x;
    int t = threadIdx.x; // 256
    float4 v = ((const float4*)(x + (size_t)l * DM))[t];
    float ss = v.x*v.x + v.y*v.y + v.z*v.z + v.w*v.w;
    #pragma unroll
    for (int m = 32; m; m >>= 1) ss += __shfl_xor(ss, m);
    __shared__ float red[4];
    if ((t & 63) == 0) red[t >> 6] = ss;
    __syncthreads();
    float tot = red[0] + red[1] + red[2] + red[3];
    float sc = rsqrtf(tot * (1.f / DM) + 1e-6f);
    float4 wv = ((const float4*)w)[t];
    float4 ov;
    ov.x = v.x * sc * wv.x;
    ov.y = v.y * sc * wv.y;
    ov.z = v.z * sc * wv.z;
    ov.w = v.w * sc * wv.w;
    ((float4*)(o + (size_t)l * DM))[t] = ov;
    if (ob) {
        uint2 pk;
        pk.x = (unsigned)f2bf(ov.x) | ((unsigned)f2bf(ov.y) << 16);
        pk.y = (unsigned)f2bf(ov.z) | ((unsigned)f2bf(ov.w) << 16);
        ((uint2*)(ob + (size_t)l * DM))[t] = pk;
    }
}

// W fp32 [K][N] -> WT bf16 [Npad][K]; rows n>=N zero-filled
__global__ void transpose_f2bf(const float* __restrict__ W, unsigned short* __restrict__ WT,
                               int K, int N) {
    __shared__ float tile[32][33];
    int k0 = blockIdx.y * 32, n0 = blockIdx.x * 32;
    int tx = threadIdx.x;  // 32
    int ty = threadIdx.y;  // 8
    #pragma unroll
    for (int i = 0; i < 32; i += 8) {
        int n = n0 + tx;
        tile[ty + i][tx] = (n < N) ? W[(size_t)(k0 + ty + i) * N + n] : 0.f;
    }
    __syncthreads();
    #pragma unroll
    for (int i = 0; i < 32; i += 8)
        WT[(size_t)(n0 + ty + i) * K + k0 + tx] = f2bf(tile[tx][ty + i]);
}

// Generic fp32 GEMM (fallback only): C = A(MxK, lda)@B(KxN) [+bias][+add][ACT]
template<int ACT>
__global__ __launch_bounds__(256) void gemm_f32(const float* __restrict__ A, int lda,
                                                const float* __restrict__ B,
                                                const float* __restrict__ bias,
                                                const float* __restrict__ add,
                                                float* __restrict__ C,
                                                int M, int N, int K) {
    __shared__ float As[16][68];
    __shared__ float Bs[16][64];
    int tx = threadIdx.x, ty = threadIdx.y;
    int t = ty * 16 + tx;
    int m0 = blockIdx.y * 64, n0 = blockIdx.x * 64;
    float acc[4][4] = {};
    for (int k0 = 0; k0 < K; k0 += 16) {
        #pragma unroll
        for (int i = 0; i < 4; i++) {
            int idx = t + i * 256;
            int mm = idx >> 4, kk = idx & 15;
            As[kk][mm] = A[(size_t)(m0 + mm) * lda + k0 + kk];
            int nn = idx & 63, k2 = idx >> 6;
            Bs[k2][nn] = B[(size_t)(k0 + k2) * N + n0 + nn];
        }
        __syncthreads();
        #pragma unroll
        for (int kk = 0; kk < 16; kk++) {
            float4 a = *(const float4*)&As[kk][ty * 4];
            float4 b = *(const float4*)&Bs[kk][tx * 4];
            acc[0][0] += a.x*b.x; acc[0][1] += a.x*b.y; acc[0][2] += a.x*b.z; acc[0][3] += a.x*b.w;
            acc[1][0] += a.y*b.x; acc[1][1] += a.y*b.y; acc[1][2] += a.y*b.z; acc[1][3] += a.y*b.w;
            acc[2][0] += a.z*b.x; acc[2][1] += a.z*b.y; acc[2][2] += a.z*b.z; acc[2][3] += a.z*b.w;
            acc[3][0] += a.w*b.x; acc[3][1] += a.w*b.y; acc[3][2] += a.w*b.z; acc[3][3] += a.w*b.w;
        }
        __syncthreads();
    }
    #pragma unroll
    for (int i = 0; i < 4; i++) {
        int row = m0 + ty * 4 + i;
        float4 r;
        float* pr = &r.x;
        #pragma unroll
        for (int j = 0; j < 4; j++) {
            int col = n0 + tx * 4 + j;
            float v = acc[i][j];
            if (bias) v += bias[col];
            if (add)  v += add[(size_t)row * N + col];
            if (ACT == 1) v = softplusf(v);
            pr[j] = v;
        }
        *(float4*)&C[(size_t)row * N + n0 + tx * 4] = r;
    }
}

// bf16 MFMA GEMM (m97 structure): C(MxN,f32) = A(bf16 [M][lda]) @ BT(bf16 [N][K])^T
// 128x128 tile, BK=32, 256 threads = 4 waves (2x2), 4x4 fragments of 16x16x32.
template<int BIAS, int ADD, int ACT>
__global__ __launch_bounds__(256) void gemm_bf16(const unsigned short* __restrict__ A, int lda,
                                                 const unsigned short* __restrict__ BT,
                                                 const float* __restrict__ bias,
                                                 const float* __restrict__ add,
                                                 float* __restrict__ C,
                                                 int M, int N, int K) {
    __shared__ unsigned short As[128 * 32];
    __shared__ unsigned short Bs[128 * 32];
    int t = threadIdx.x;
    int w = t >> 6, l = t & 63;
    int wm = w >> 1, wn = w & 1;
    int m0 = blockIdx.x * 128;   // M-tiles on x: consecutive blocks share B panel (L2)
    int n0 = blockIdx.y * 128;
    int lr = l & 15, lk = (l >> 4) * 8;
    int sr = t >> 2, sc = (t & 3) * 8;     // staging: row, k-offset
    f32x4 acc[4][4] = {};
    for (int k0 = 0; k0 < K; k0 += 32) {
        const unsigned short* ga = A  + (size_t)(m0 + sr) * lda + k0 + sc;
        const unsigned short* gb = BT + (size_t)(n0 + sr) * K + k0 + sc;
        unsigned short* la = As + w * 512;   // wave-uniform base; HW adds lane*16B
        unsigned short* lb = Bs + w * 512;
        __builtin_amdgcn_global_load_lds((const __attribute__((address_space(1))) void*)ga,
            (__attribute__((address_space(3))) void*)la, 16, 0, 0);
        __builtin_amdgcn_global_load_lds((const __attribute__((address_space(1))) void*)(ga + (size_t)64 * lda),
            (__attribute__((address_space(3))) void*)(la + 2048), 16, 0, 0);
        __builtin_amdgcn_global_load_lds((const __attribute__((address_space(1))) void*)gb,
            (__attribute__((address_space(3))) void*)(lb), 16, 0, 0);
        __builtin_amdgcn_global_load_lds((const __attribute__((address_space(1))) void*)(gb + (size_t)64 * K),
            (__attribute__((address_space(3))) void*)(lb + 2048), 16, 0, 0);
        __syncthreads();
        bf16x8 af[4], bfr[4];
        #pragma unroll
        for (int i = 0; i < 4; i++) {
            af[i]  = *reinterpret_cast<const bf16x8*>(&As[(wm * 64 + i * 16 + lr) * 32 + lk]);
            bfr[i] = *reinterpret_cast<const bf16x8*>(&Bs[(wn * 64 + i * 16 + lr) * 32 + lk]);
        }
        #pragma unroll
        for (int i = 0; i < 4; i++)
            #pragma unroll
            for (int j = 0; j < 4; j++)
                acc[i][j] = __builtin_amdgcn_mfma_f32_16x16x32_bf16(af[i], bfr[j], acc[i][j], 0, 0, 0);
        __syncthreads();
    }
    int cr = (l >> 4) * 4;
    #pragma unroll
    for (int i = 0; i < 4; i++) {
        #pragma unroll
        for (int j = 0; j < 4; j++) {
            int col = n0 + wn * 64 + j * 16 + lr;
            float bv = BIAS ? bias[col] : 0.f;
            #pragma unroll
            for (int rr = 0; rr < 4; rr++) {
                int row = m0 + wm * 64 + i * 16 + cr + rr;
                float v = acc[i][j][rr] + bv;
                if (ADD) v += add[(size_t)row * N + col];
                if (ACT == 1) v = softplusf(v);
                C[(size_t)row * N + col] = v;
            }
        }
    }
}

// xc[l,d] = silu(conv_b[l] + sum_k x[l, d+k-1]*conv_w[k,l])   (conv over d!)
__global__ void conv_silu_kernel(const float* __restrict__ xr, const float* __restrict__ cw,
                                 const float* __restrict__ cb, float* __restrict__ xc) {
    int idx = blockIdx.x * 256 + threadIdx.x;
    int l = idx >> 11, d = idx & 2047;
    float acc = cb[l];
    const float* xrow = xr + (size_t)l * 4096;
    #pragma unroll
    for (int k = 0; k < 4; k++) {
        int c = d + k - 1;
        if (c >= 0 && c < DI) acc += xrow[c] * cw[k * SEQ + l];
    }
    xc[idx] = siluf(acc);
}

// fallback xproj (fp32, stride-128 output)
__global__ void xproj_kernel(const float* __restrict__ u, const float* __restrict__ xw,
                             float* __restrict__ xdbl) {
    int l0 = blockIdx.x * 4;
    int t = threadIdx.x; // 128
    __shared__ float us[4][DM];
    for (int i = t; i < 4 * DM; i += 128) us[i >> 10][i & 1023] = u[(size_t)l0 * DM + i];
    __syncthreads();
    if (t < 96) {
        float a0 = 0.f, a1 = 0.f, a2 = 0.f, a3 = 0.f;
        for (int k = 0; k < DM; k++) {
            float wv = xw[(size_t)k * 96 + t];
            a0 += us[0][k] * wv; a1 += us[1][k] * wv;
            a2 += us[2][k] * wv; a3 += us[3][k] * wv;
        }
        xdbl[(size_t)(l0 + 0) * 128 + t] = a0;
        xdbl[(size_t)(l0 + 1) * 128 + t] = a1;
        xdbl[(size_t)(l0 + 2) * 128 + t] = a2;
        xdbl[(size_t)(l0 + 3) * 128 + t] = a3;
    }
}

// xdbl[:, 0:64] f32 -> bf16 for the dt_proj MFMA GEMM
__global__ void cvt_delta(const float* __restrict__ xdbl, unsigned short* __restrict__ db) {
    int idx = blockIdx.x * 256 + threadIdx.x;   // over SEQ*64
    int l = idx >> 6, q = idx & 63;
    db[idx] = f2bf(xdbl[(size_t)l * 128 + q]);
}

// ---- chunked selective scan ----
// thread owns one d and all 16 n-states. xdbl stride 128: B at +64, C at +80.
// Pass 1: per (chunk c, d): local scan from 0 -> S[c,d,n]; decay P[c,d,n]=exp(a_n*sum dv)
__global__ __launch_bounds__(256) void scan_p1(const float* __restrict__ xc,
        const float* __restrict__ delta, const float* __restrict__ xdbl,
        const float* __restrict__ A_log, float* __restrict__ P, float* __restrict__ S) {
    int c = blockIdx.x;
    int d = blockIdx.y * 256 + threadIdx.x;
    int l0 = c * LC;
    __shared__ float Bsh[LC][16];
    {
        int t = threadIdx.x;   // 256 = LC*16 exactly
        int ll = t >> 4, q = t & 15;
        Bsh[ll][q] = xdbl[(size_t)(l0 + ll) * 128 + 64 + q];
    }
    __syncthreads();
    float a[16];
    #pragma unroll
    for (int i = 0; i < 4; i++) {
        float4 al = ((const float4*)(A_log + (size_t)d * 16))[i];
        a[4*i+0] = -expf(al.x); a[4*i+1] = -expf(al.y);
        a[4*i+2] = -expf(al.z); a[4*i+3] = -expf(al.w);
    }
    float s[16] = {};
    float sumdv = 0.f;
    for (int ll = 0; ll < LC; ll++) {
        float dv = delta[(size_t)(l0 + ll) * DI + d];
        float xv = xc[(size_t)(l0 + ll) * DI + d];
        float du = dv * xv;
        sumdv += dv;
        #pragma unroll
        for (int n = 0; n < 16; n++)
            s[n] = expf(dv * a[n]) * s[n] + du * Bsh[ll][n];
    }
    size_t o = ((size_t)c * DI + d) * 16;
    #pragma unroll
    for (int i = 0; i < 4; i++) {
        float4 sv = make_float4(s[4*i], s[4*i+1], s[4*i+2], s[4*i+3]);
        float4 pv = make_float4(expf(a[4*i]*sumdv), expf(a[4*i+1]*sumdv),
                                expf(a[4*i+2]*sumdv), expf(a[4*i+3]*sumdv));
        ((float4*)(S + o))[i] = sv;
        ((float4*)(P + o))[i] = pv;
    }
}

// Pass 2: compose chunk states serially: X[c] = state entering chunk c
__global__ void scan_p2(const float* __restrict__ P, const float* __restrict__ S,
                        float* __restrict__ X) {
    int t = blockIdx.x * 256 + threadIdx.x;   // 0 .. DI*16-1
    float x = 0.f;
    #pragma unroll 16
    for (int c = 0; c < NC; c++) {
        X[(size_t)c * (DI*16) + t] = x;
        x = P[(size_t)c * (DI*16) + t] * x + S[(size_t)c * (DI*16) + t];
    }
}

// Pass 3: re-run chunk from true initial state, emit y
__global__ __launch_bounds__(256) void scan_p3(const float* __restrict__ xc,
        const float* __restrict__ delta, const float* __restrict__ xdbl,
        const float* __restrict__ A_log, const float* __restrict__ Dp,
        const float* __restrict__ X, float* __restrict__ y) {
    int c = blockIdx.x;
    int d = blockIdx.y * 256 + threadIdx.x;
    int l0 = c * LC;
    __shared__ float Bsh[LC][16], Csh[LC][16];
    {
        int t = threadIdx.x;
        int ll = t >> 4, q = t & 15;
        size_t row = (size_t)(l0 + ll) * 128;
        Bsh[ll][q] = xdbl[row + 64 + q];
        Csh[ll][q] = xdbl[row + 80 + q];
    }
    __syncthreads();
    float a[16];
    #pragma unroll
    for (int i = 0; i < 4; i++) {
        float4 al = ((const float4*)(A_log + (size_t)d * 16))[i];
        a[4*i+0] = -expf(al.x); a[4*i+1] = -expf(al.y);
        a[4*i+2] = -expf(al.z); a[4*i+3] = -expf(al.w);
    }
    float s[16];
    size_t o = ((size_t)c * DI + d) * 16;
    #pragma unroll
    for (int i = 0; i < 4; i++) {
        float4 xv4 = ((const float4*)(X + o))[i];
        s[4*i] = xv4.x; s[4*i+1] = xv4.y; s[4*i+2] = xv4.z; s[4*i+3] = xv4.w;
    }
    float Dv = Dp[d];
    for (int ll = 0; ll < LC; ll++) {
        float dv = delta[(size_t)(l0 + ll) * DI + d];
        float xv = xc[(size_t)(l0 + ll) * DI + d];
        float du = dv * xv;
        float yv = 0.f;
        #pragma unroll
        for (int n = 0; n < 16; n++) {
            s[n] = expf(dv * a[n]) * s[n] + du * Bsh[ll][n];
            yv += s[n] * Csh[ll][n];
        }
        y[(size_t)(l0 + ll) * DI + d] = yv + xv * Dv;
    }
}

// y *= silu(res); optional bf16 copy
__global__ void ymul_silu(float* __restrict__ y, const float* __restrict__ xr,
                          unsigned short* __restrict__ yb) {
    int idx = blockIdx.x * 256 + threadIdx.x;
    int l = idx >> 11, d = idx & 2047;
    float res = xr[(size_t)l * 4096 + 2048 + d];
    float v = y[idx] * siluf(res);
    y[idx] = v;
    if (yb) yb[idx] = f2bf(v);
}

extern "C" void kernel_launch(void* const* d_in, const int* in_sizes, int n_in,
                              void* d_out, int out_size, void* d_ws, size_t ws_size,
                              hipStream_t stream) {
    const int*   ids        = (const int*)d_in[0];
    const float* embed      = (const float*)d_in[1];
    const float* norm_scale = (const float*)d_in[2];
    const float* in_w       = (const float*)d_in[3];
    const float* in_b       = (const float*)d_in[4];
    const float* conv_w     = (const float*)d_in[5];
    const float* conv_b     = (const float*)d_in[6];
    const float* x_proj_w   = (const float*)d_in[7];
    const float* dt_w       = (const float*)d_in[8];
    const float* dt_b       = (const float*)d_in[9];
    const float* out_w      = (const float*)d_in[10];
    const float* out_b      = (const float*)d_in[11];
    const float* A_log      = (const float*)d_in[12];
    const float* Dp         = (const float*)d_in[13];
    const float* norm_f     = (const float*)d_in[14];
    const float* lm_w       = (const float*)d_in[15];

    float* out = (float*)d_out;

    // ---- workspace layout ----
    char* p = (char*)d_ws;
    float* h  = (float*)p;  p += (size_t)SEQ * DM * 4;
    float* hn = (float*)p;  p += (size_t)SEQ * DM * 4;
    size_t base = (size_t)p - (size_t)d_ws;
    const size_t SZ_UB    = (size_t)SEQ * DM * 2;
    const size_t SZ_YB    = (size_t)SEQ * DI * 2;
    const size_t SZ_HNB   = (size_t)SEQ * DM * 2;
    const size_t SZ_DB    = (size_t)SEQ * 64 * 2;
    const size_t SZ_INWT  = (size_t)2 * 4096 * DM * 2;
    const size_t SZ_OUTWT = (size_t)2 * DM * DI * 2;
    const size_t SZ_XPWT  = (size_t)2 * 128 * DM * 2;
    const size_t SZ_DTWT  = (size_t)2 * DI * 64 * 2;
    const size_t SZ_LMWT  = (size_t)NVOC * DM * 2;
    size_t need_mid  = base + SZ_UB + SZ_YB + SZ_HNB + SZ_DB + SZ_INWT + SZ_OUTWT + SZ_XPWT + SZ_DTWT;
    size_t need_full = need_mid + SZ_LMWT;
    bool mid  = ws_size >= need_mid;
    bool full = ws_size >= need_full;

    unsigned short *u_b = nullptr, *y_b = nullptr, *hn_b = nullptr, *dlt_b = nullptr;
    unsigned short *in_wT = nullptr, *out_wT = nullptr, *xp_wT = nullptr, *dt_wT = nullptr, *lm_wT = nullptr;
    if (mid) {
        u_b    = (unsigned short*)p; p += SZ_UB;
        y_b    = (unsigned short*)p; p += SZ_YB;
        hn_b   = (unsigned short*)p; p += SZ_HNB;
        dlt_b  = (unsigned short*)p; p += SZ_DB;
        in_wT  = (unsigned short*)p; p += SZ_INWT;
        out_wT = (unsigned short*)p; p += SZ_OUTWT;
        xp_wT  = (unsigned short*)p; p += SZ_XPWT;
        dt_wT  = (unsigned short*)p; p += SZ_DTWT;
        if (full) { lm_wT = (unsigned short*)p; p += SZ_LMWT; }
    }

    // transient scratch inside d_out (fully rewritten by final GEMM)
    float* u     = out;                          // SEQ*DM
    float* xr    = u + (size_t)SEQ * DM;         // SEQ*4096
    float* xc    = xr + (size_t)SEQ * 4096;      // SEQ*DI
    float* xdbl  = xc + (size_t)SEQ * DI;        // SEQ*128
    float* delta = xdbl + (size_t)SEQ * 128;     // SEQ*DI
    float* y     = delta + (size_t)SEQ * DI;     // SEQ*DI
    float* Pbuf  = y + (size_t)SEQ * DI;         // NC*DI*16
    float* Sbuf  = Pbuf + (size_t)NC * DI * 16;  // NC*DI*16
    float* Xbuf  = Sbuf + (size_t)NC * DI * 16;  // NC*DI*16

    // ---- weight convert+transpose (per call; deterministic) ----
    if (mid) {
        for (int L = 0; L < 2; L++) {
            transpose_f2bf<<<dim3(4096 / 32, DM / 32), dim3(32, 8), 0, stream>>>(
                in_w + (size_t)L * DM * 4096, in_wT + (size_t)L * 4096 * DM, DM, 4096);
            transpose_f2bf<<<dim3(DM / 32, DI / 32), dim3(32, 8), 0, stream>>>(
                out_w + (size_t)L * DI * DM, out_wT + (size_t)L * DM * DI, DI, DM);
            transpose_f2bf<<<dim3(128 / 32, DM / 32), dim3(32, 8), 0, stream>>>(
                x_proj_w + (size_t)L * DM * 96, xp_wT + (size_t)L * 128 * DM, DM, 96);
            transpose_f2bf<<<dim3(DI / 32, 64 / 32), dim3(32, 8), 0, stream>>>(
                dt_w + (size_t)L * DTR * DI, dt_wT + (size_t)L * DI * 64, DTR, DI);
        }
        if (full)
            transpose_f2bf<<<dim3(NVOC / 32, DM / 32), dim3(32, 8), 0, stream>>>(
                lm_w, lm_wT, DM, NVOC);
    }

    embed_gather<<<SEQ, 256, 0, stream>>>(ids, embed, h);

    for (int L = 0; L < 2; L++) {
        rmsnorm_kernel<<<SEQ, 256, 0, stream>>>(h, norm_scale + (size_t)L * DM, u, u_b);
        if (mid) {
            gemm_bf16<1, 0, 0><<<dim3(SEQ / 128, 4096 / 128), 256, 0, stream>>>(
                u_b, DM, in_wT + (size_t)L * 4096 * DM, in_b + (size_t)L * 4096, nullptr, xr,
                SEQ, 4096, DM);
        } else {
            gemm_f32<0><<<dim3(4096 / 64, SEQ / 64), dim3(16, 16), 0, stream>>>(
                u, DM, in_w + (size_t)L * DM * 4096, in_b + (size_t)L * 4096, nullptr, xr,
                SEQ, 4096, DM);
        }
        conv_silu_kernel<<<SEQ * DI / 256, 256, 0, stream>>>(
            xr, conv_w + (size_t)L * 4 * SEQ, conv_b + (size_t)L * SEQ, xc);
        if (mid) {
            gemm_bf16<0, 0, 0><<<dim3(SEQ / 128, 1), 256, 0, stream>>>(
                u_b, DM, xp_wT + (size_t)L * 128 * DM, nullptr, nullptr, xdbl,
                SEQ, 128, DM);
            cvt_delta<<<SEQ * 64 / 256, 256, 0, stream>>>(xdbl, dlt_b);
            gemm_bf16<1, 0, 1><<<dim3(SEQ / 128, DI / 128), 256, 0, stream>>>(
                dlt_b, 64, dt_wT + (size_t)L * DI * 64, dt_b + (size_t)L * DI, nullptr, delta,
                SEQ, DI, 64);
        } else {
            xproj_kernel<<<SEQ / 4, 128, 0, stream>>>(u, x_proj_w + (size_t)L * DM * 96, xdbl);
            gemm_f32<1><<<dim3(DI / 64, SEQ / 64), dim3(16, 16), 0, stream>>>(
                xdbl, 128, dt_w + (size_t)L * DTR * DI, dt_b + (size_t)L * DI, nullptr, delta,
                SEQ, DI, DTR);
        }
        scan_p1<<<dim3(NC, DI / 256), 256, 0, stream>>>(
            xc, delta, xdbl, A_log + (size_t)L * DI * DST, Pbuf, Sbuf);
        scan_p2<<<DI * 16 / 256, 256, 0, stream>>>(Pbuf, Sbuf, Xbuf);
        scan_p3<<<dim3(NC, DI / 256), 256, 0, stream>>>(
            xc, delta, xdbl, A_log + (size_t)L * DI * DST, Dp + (size_t)L * DI, Xbuf, y);
        ymul_silu<<<SEQ * DI / 256, 256, 0, stream>>>(y, xr, y_b);
        if (mid) {
            gemm_bf16<1, 1, 0><<<dim3(SEQ / 128, DM / 128), 256, 0, stream>>>(
                y_b, DI, out_wT + (size_t)L * DM * DI, out_b + (size_t)L * DM, h, h,
                SEQ, DM, DI);
        } else {
            gemm_f32<0><<<dim3(DM / 64, SEQ / 64), dim3(16, 16), 0, stream>>>(
                y, DI, out_w + (size_t)L * DI * DM, out_b + (size_t)L * DM, h, h,
                SEQ, DM, DI);
        }
    }

    rmsnorm_kernel<<<SEQ, 256, 0, stream>>>(h, norm_f, hn, hn_b);
    if (full) {
        gemm_bf16<0, 0, 0><<<dim3(SEQ / 128, NVOC / 128), 256, 0, stream>>>(
            hn_b, DM, lm_wT, nullptr, nullptr, out, SEQ, NVOC, DM);
    } else {
        gemm_f32<0><<<dim3(NVOC / 64, SEQ / 64), dim3(16, 16), 0, stream>>>(
            hn, DM, lm_w, nullptr, nullptr, out, SEQ, NVOC, DM);
    }
}